// Round 8
// baseline (646.587 us; speedup 1.0000x reference)
//
#include <hip/hip_runtime.h>

// ---------------- constants ----------------
#define BB 2
#define SEQ 4096
#define LQ 4064
#define HID 1024
#define NH 16
#define HD 64
#define NB 64      // number of 64-wide blocks in sequence
#define BLK 64
#define NR 3
#define PENV -10000.0f

typedef __bf16 bf16;
typedef __bf16 bf16x8 __attribute__((ext_vector_type(8)));
typedef float floatx4 __attribute__((ext_vector_type(4)));

__device__ inline floatx4 mfma16(bf16x8 a, bf16x8 b, floatx4 c) {
    return __builtin_amdgcn_mfma_f32_16x16x32_bf16(a, b, c, 0, 0, 0);
}

// async global->LDS, 16B per lane (global_load_lds_dwordx4)
__device__ inline void async_ld16(const bf16* g, bf16* l) {
    __builtin_amdgcn_global_load_lds(
        (const __attribute__((address_space(1))) unsigned int*)g,
        (__attribute__((address_space(3))) unsigned int*)l, 16, 0, 0);
}

// ---------------- prep: pad + cast X to bf16 ----------------
__global__ __launch_bounds__(256) void cast_pad_x(const float* __restrict__ X,
                                                  bf16* __restrict__ Xp) {
    int t = blockIdx.x * 256 + threadIdx.x;
    int c4 = t & 255;
    int row = t >> 8;
    int b = row >> 12;
    int s = row & 4095;
    float4 v = make_float4(0.f, 0.f, 0.f, 0.f);
    if (s < LQ) {
        v = reinterpret_cast<const float4*>(X + ((size_t)(b * LQ + s)) * HID)[c4];
    }
    union { bf16 h[4]; uint2 u; } o;
    o.h[0] = (bf16)v.x; o.h[1] = (bf16)v.y; o.h[2] = (bf16)v.z; o.h[3] = (bf16)v.w;
    *reinterpret_cast<uint2*>(Xp + (size_t)row * HID + c4 * 4) = o.u;
}

// ---------------- prep: transpose + cast weights ----------------
__global__ __launch_bounds__(256) void transpose_w(const float* __restrict__ Wq,
                                                   const float* __restrict__ Wk,
                                                   const float* __restrict__ Wv,
                                                   const float* __restrict__ Wo,
                                                   bf16* __restrict__ WqkvT,
                                                   bf16* __restrict__ WoT) {
    __shared__ float tile[64][65];
    int sel = blockIdx.z;
    const float* src = (sel == 0) ? Wq : (sel == 1) ? Wk : (sel == 2) ? Wv : Wo;
    bf16* dst = (sel < 3) ? (WqkvT + (size_t)sel * HID * HID) : WoT;
    int j0 = blockIdx.x * 64, k0 = blockIdx.y * 64;
    int tx = threadIdx.x, ty = threadIdx.y;   // (64,4)
    for (int i = 0; i < 16; i++) {
        int k = ty + i * 4;
        tile[k][tx] = src[(size_t)(k0 + k) * HID + j0 + tx];
    }
    __syncthreads();
    for (int i = 0; i < 16; i++) {
        int j = ty + i * 4;
        dst[(size_t)(j0 + j) * HID + k0 + tx] = (bf16)tile[tx][j];
    }
}

// ---------------- prep: transpose band mask ----------------
// band[b][l][q=64][k=192] -> bandT[b][l][k=192][q=64]
__global__ __launch_bounds__(256) void transpose_band(const float* __restrict__ band,
                                                      float* __restrict__ bandT) {
    __shared__ float tile[64][65];
    int kt = blockIdx.x;           // 0..2
    int lrow = blockIdx.y;         // 0..59
    int b = blockIdx.z;
    const float* src = band + ((size_t)(b * (NB - 4) + lrow) * BLK) * 192;
    float* dst = bandT + ((size_t)(b * (NB - 4) + lrow) * 192) * BLK;
    int tx = threadIdx.x, ty = threadIdx.y;   // (64,4)
    for (int i = 0; i < 16; i++) {
        int qq = i * 4 + ty;
        tile[qq][tx] = src[(size_t)qq * 192 + kt * 64 + tx];
    }
    __syncthreads();
    for (int i = 0; i < 16; i++) {
        int k = i * 4 + ty;
        dst[(size_t)(kt * 64 + k) * BLK + tx] = tile[tx][k];
    }
}

// ---------------- prep: all-ones flags for the three masks ----------------
// flags[which*BB+b] = 1 iff every element of that mask slice is exactly 1.0f.
// which: 0=to_mask, 1=blocked, 2=band. Skipping a mask whose flag=1 is exact:
// (1-1)*PEN == 0.
__global__ __launch_bounds__(256) void mask_flags(const float* __restrict__ tom,
                                                  const float* __restrict__ blocked,
                                                  const float* __restrict__ band,
                                                  int* __restrict__ flags) {
    int which = blockIdx.x, b = blockIdx.y;
    const float* src;
    size_t n;
    if (which == 0)      { src = tom     + (size_t)b * SEQ;                  n = SEQ; }
    else if (which == 1) { src = blocked + (size_t)b * NB * BLK;             n = NB * BLK; }
    else                 { src = band    + (size_t)b * (NB - 4) * BLK * 192; n = (size_t)(NB - 4) * BLK * 192; }
    const float4* s4 = (const float4*)src;
    size_t n4 = n >> 2;
    int ok = 1;
    for (size_t i = threadIdx.x; i < n4; i += 256) {
        float4 v = s4[i];
        ok &= (v.x == 1.0f) & (v.y == 1.0f) & (v.z == 1.0f) & (v.w == 1.0f);
    }
    ok = __all(ok) ? 1 : 0;
    __shared__ int sh;
    if (threadIdx.x == 0) sh = 1;
    __syncthreads();
    if ((threadIdx.x & 63) == 0 && !ok) atomicAnd(&sh, 0);
    __syncthreads();
    if (threadIdx.x == 0) flags[which * BB + b] = sh;
}

// ---------------- GEMM1: QKV projection ----------------
// 1-D grid, XCD-striped; LDS-transposed coalesced epilogue ([s][d] q/k, [d][s] v).
__global__ __launch_bounds__(256) void gemm_qkv(const bf16* __restrict__ Xp,
                                                const bf16* __restrict__ WT,
                                                const float* __restrict__ bq,
                                                const float* __restrict__ bk,
                                                const float* __restrict__ bv,
                                                bf16* __restrict__ qo,
                                                bf16* __restrict__ ko,
                                                bf16* __restrict__ vt) {
    __shared__ __align__(16) char smem[36864];   // staging 32KB; epi 4x9216B overlays
    bf16* As = (bf16*)smem;            // [128][64]
    bf16* Bs = As + 128 * 64;          // [128][64]
    int tid = threadIdx.x;
    int wave = tid >> 6, lane = tid & 63;
    int quad = lane >> 4, lm = lane & 15;
    int id = blockIdx.x;
    int xcd = id & 7, slot = id >> 3;
    int tile_m = (xcd * 8 + (slot & 7)) * 128;   // 64 tile_m rows across 8 XCDs
    int tile_n = (slot >> 3) * 128;              // 24 tile_n cols
    int wm = (wave & 1) * 64, wn = (wave >> 1) * 64;

    floatx4 acc[4][4] = {};

    for (int k0 = 0; k0 < HID; k0 += 64) {
        __syncthreads();
        for (int it = 0; it < 4; it++) {
            int c = it * 256 + tid;           // LDS offset = c*16B (lane-contig)
            int row = c >> 3, col = (c & 7) * 8;
            async_ld16(Xp + (size_t)(tile_m + row) * HID + k0 + col, &As[c * 8]);
            async_ld16(WT + (size_t)(tile_n + row) * HID + k0 + col, &Bs[c * 8]);
        }
        __syncthreads();
        for (int ks = 0; ks < 64; ks += 32) {
            bf16x8 a[4], b[4];
            for (int i = 0; i < 4; i++)
                a[i] = *reinterpret_cast<const bf16x8*>(&As[(wm + i * 16 + lm) * 64 + ks + quad * 8]);
            for (int j = 0; j < 4; j++)
                b[j] = *reinterpret_cast<const bf16x8*>(&Bs[(wn + j * 16 + lm) * 64 + ks + quad * 8]);
            for (int i = 0; i < 4; i++)
                for (int j = 0; j < 4; j++)
                    acc[i][j] = mfma16(a[i], b[j], acc[i][j]);
        }
    }

    int which = tile_n >> 10;                 // 0=q,1=k,2=v (wave-uniform)
    int hc_base = (tile_n + wn) & 1023;       // multiple of 64
    int h = hc_base >> 6;
    const float* bias = (which == 0) ? bq : (which == 1) ? bk : bv;
    __syncthreads();                          // retire all staging reads before overlay
    bf16* ep = (bf16*)smem + wave * (64 * 72);

    if (which < 2) {
        #pragma unroll
        for (int i = 0; i < 4; i++)
            #pragma unroll
            for (int j = 0; j < 4; j++) {
                float bsv = bias[hc_base + j * 16 + lm];
                #pragma unroll
                for (int r = 0; r < 4; r++) {
                    float val = acc[i][j][r] + bsv;
                    if (which == 0) val *= 0.125f;
                    ep[(i * 16 + quad * 4 + r) * 72 + j * 16 + lm] = (bf16)val;
                }
            }
        __builtin_amdgcn_wave_barrier();
        int s_glob = tile_m + wm + lane;
        int b_ = s_glob >> 12, s = s_glob & 4095;
        bf16* dstb = ((which == 0) ? qo : ko) + ((size_t)((b_ * NH + h) * SEQ + s)) * HD;
        #pragma unroll
        for (int c = 0; c < 8; c++)
            *reinterpret_cast<uint4*>(dstb + c * 8) =
                *reinterpret_cast<const uint4*>(ep + lane * 72 + c * 8);
    } else {
        #pragma unroll
        for (int i = 0; i < 4; i++)
            #pragma unroll
            for (int j = 0; j < 4; j++) {
                float bsv = bias[hc_base + j * 16 + lm];
                #pragma unroll
                for (int r = 0; r < 4; r++) {
                    float val = acc[i][j][r] + bsv;
                    ep[(j * 16 + lm) * 72 + i * 16 + quad * 4 + r] = (bf16)val;
                }
            }
        __builtin_amdgcn_wave_barrier();
        int s_base = tile_m + wm;
        int b_ = s_base >> 12, s0 = s_base & 4095;
        bf16* dstb = vt + ((size_t)((b_ * NH + h) * HD + lane)) * SEQ + s0;
        #pragma unroll
        for (int c = 0; c < 8; c++)
            *reinterpret_cast<uint4*>(dstb + c * 8) =
                *reinterpret_cast<const uint4*>(ep + lane * 72 + c * 8);
    }
}

// ---------------- attention (S^T formulation, 512-thread wg, paired waves) ----------------
// grid: (B*NH, 70). blockIdx.x = bh -> XCD-resident K/V per (b,h).
// y<8: full rows. l=(y>>2)?63:0, sub=y&3 (whole wg on one 16-query subtile);
//      wave w covers blocks w*8..w*8+8 (2 chunks of 4); 8-partial LDS combine.
// y>=8: middle row l=y-7. wave w: subtile=w&3, half=w>>2 -> ONE chunk of 4 from the
//      8-padded block list; pairwise (w, w+4) LDS combine. Halves the per-wave
//      serial chain vs the 4-wave version.
// Mask penalties are skipped wave-uniformly when the mask is all-ones (flags).
__global__ __launch_bounds__(512, 4) void attn_kernel(const bf16* __restrict__ q,
                                                      const bf16* __restrict__ kk,
                                                      const bf16* __restrict__ vt,
                                                      const float* __restrict__ bandT,
                                                      const float* __restrict__ fromm,
                                                      const float* __restrict__ tom,
                                                      const float* __restrict__ blocked,
                                                      const int* __restrict__ rand_attn,
                                                      const int* __restrict__ flags,
                                                      bf16* __restrict__ attn) {
    // loop phase: per-wave P regions [16 q][136] bf16 (4352 B x 8 = 34816 B)
    // epilogue overlay: ctxL[8][64][16] f32 (32 KB) + mL/lL [8][16]
    __shared__ __align__(16) char smem[34816 + 1024];

    int tid = threadIdx.x, wave = tid >> 6, lane = tid & 63;
    int quad = lane >> 4, lm = lane & 15;
    int bh = blockIdx.x;
    int b = bh >> 4, h = bh & 15;
    size_t bh_base = (size_t)bh * SEQ * HD;
    int y = blockIdx.y;
    bool fullmode = (y < 8);
    int l, sub, half;
    if (fullmode) { l = (y >> 2) ? (NB - 1) : 0; sub = y & 3;    half = 0; }
    else          { l = y - 7;                   sub = wave & 3; half = wave >> 2; }

    bool sk_to = flags[b] != 0;
    bool sk_bl = flags[2 + b] != 0;
    bool sk_bd = flags[4 + b] != 0;

    // Q fragments (B-operand: n=query=lm, k=d=quad*8+j); q pre-scaled by 1/sqrt(D)
    bf16x8 aq0 = *reinterpret_cast<const bf16x8*>(
        q + bh_base + (size_t)(l * BLK + sub * 16 + lm) * HD + quad * 8);
    bf16x8 aq1 = *reinterpret_cast<const bf16x8*>(
        q + bh_base + (size_t)(l * BLK + sub * 16 + lm) * HD + 32 + quad * 8);

    floatx4 ctx[4] = {};        // O^T: d=dj*16+quad*4+r, query=lm
    float mrun = -1e30f, lrun = 0.f;
    float mq = blocked[((size_t)b * NB + l) * BLK + sub * 16 + lm];  // per-lane query mask

    // key-block list (middle mode), padded to 8. type: 0=to_mask, 1..3=band(t), 4=rand, 5=pad
    int blist[8], btype[8];
    if (!fullmode) {
        int base;
        if (l == 1) {
            blist[0] = 0; blist[1] = 1; blist[2] = 2; blist[3] = NB - 1;
            btype[0] = btype[1] = btype[2] = btype[3] = 0;
            base = 4;
        } else if (l == NB - 2) {
            blist[0] = 0; blist[1] = NB - 3; blist[2] = NB - 2; blist[3] = NB - 1;
            btype[0] = btype[1] = btype[2] = btype[3] = 0;
            base = 4;
        } else {
            blist[0] = 0;      btype[0] = 0;
            blist[1] = l - 1;  btype[1] = 1;
            blist[2] = l;      btype[2] = 2;
            blist[3] = l + 1;  btype[3] = 3;
            blist[4] = NB - 1; btype[4] = 0;
            base = 5;
        }
        const int* ra = rand_attn + ((size_t)(b * NH + h) * (NB - 2) + (l - 1)) * NR;
        for (int r = 0; r < NR; r++) { blist[base + r] = ra[r]; btype[base + r] = 4; }
        for (int i = base + NR; i < 8; i++) { blist[i] = 0; btype[i] = 5; }
    }

    bf16* pw = (bf16*)smem + wave * 16 * 136;  // [q=16][key stride 136] (2 blocks/phase)

    int nch = fullmode ? 2 : 1;
    for (int ch = 0; ch < nch; ch++) {
        // ---- scores: S^T = K * Q^T; sc[ib][f][r] = S^T[key=f*16+quad*4+r][q=lm] ----
        floatx4 sc[4][4];
        #pragma unroll
        for (int ib = 0; ib < 4; ib++) {
            int kb  = fullmode ? (wave * 8 + ch * 4 + ib) : blist[half * 4 + ib];
            int typ = fullmode ? 0 : btype[half * 4 + ib];
            const bf16* kbase = kk + bh_base + (size_t)kb * BLK * HD;
            #pragma unroll
            for (int f = 0; f < 4; f++) {
                bf16x8 a0 = *reinterpret_cast<const bf16x8*>(kbase + (f * 16 + lm) * HD + quad * 8);
                bf16x8 a1 = *reinterpret_cast<const bf16x8*>(kbase + (f * 16 + lm) * HD + 32 + quad * 8);
                floatx4 z = {0.f, 0.f, 0.f, 0.f};
                z = mfma16(a0, aq0, z);
                z = mfma16(a1, aq1, z);
                sc[ib][f] = z;
            }
            // masks (key = f*16+quad*4+r, query = lm); skipped when mask all-ones
            if (typ == 0) {
                if (!sk_to) {
                    #pragma unroll
                    for (int f = 0; f < 4; f++) {
                        float4 t4 = *reinterpret_cast<const float4*>(
                            tom + (size_t)b * SEQ + kb * BLK + f * 16 + quad * 4);
                        sc[ib][f][0] += (1.f - t4.x) * PENV;
                        sc[ib][f][1] += (1.f - t4.y) * PENV;
                        sc[ib][f][2] += (1.f - t4.z) * PENV;
                        sc[ib][f][3] += (1.f - t4.w) * PENV;
                    }
                }
            } else if (typ == 4) {
                if (!sk_bl) {
                    #pragma unroll
                    for (int f = 0; f < 4; f++) {
                        float4 t4 = *reinterpret_cast<const float4*>(
                            blocked + ((size_t)b * NB + kb) * BLK + f * 16 + quad * 4);
                        sc[ib][f][0] += (1.f - mq * t4.x) * PENV;
                        sc[ib][f][1] += (1.f - mq * t4.y) * PENV;
                        sc[ib][f][2] += (1.f - mq * t4.z) * PENV;
                        sc[ib][f][3] += (1.f - mq * t4.w) * PENV;
                    }
                }
            } else if (typ != 5) {
                if (!sk_bd) {
                    int t = typ - 1;
                    const float* bp = bandT + ((size_t)(b * (NB - 4) + (l - 2)) * 192 + t * 64) * BLK;
                    #pragma unroll
                    for (int f = 0; f < 4; f++)
                        #pragma unroll
                        for (int r = 0; r < 4; r++) {
                            float bm = bp[(size_t)(f * 16 + quad * 4 + r) * BLK + sub * 16 + lm];
                            sc[ib][f][r] += (1.f - bm) * PENV;
                        }
                }
            } else {
                #pragma unroll
                for (int f = 0; f < 4; f++)
                    #pragma unroll
                    for (int r = 0; r < 4; r++) sc[ib][f][r] += PENV;
            }
        }

        // ---- softmax over the chunk (per-lane m; 2 shuffles) ----
        float mx = -1e30f;
        #pragma unroll
        for (int ib = 0; ib < 4; ib++)
            #pragma unroll
            for (int f = 0; f < 4; f++)
                #pragma unroll
                for (int r = 0; r < 4; r++) mx = fmaxf(mx, sc[ib][f][r]);
        mx = fmaxf(mx, __shfl_xor(mx, 16, 64));
        mx = fmaxf(mx, __shfl_xor(mx, 32, 64));
        float mnew = fmaxf(mrun, mx);
        float scale = __expf(mrun - mnew);
        lrun *= scale;
        #pragma unroll
        for (int dj = 0; dj < 4; dj++) ctx[dj] *= scale;
        mrun = mnew;

        // ---- exp -> P^T via per-wave LDS (2 blocks per phase) -> PV^T MFMAs ----
        float rs = 0.f;
        #pragma unroll
        for (int p = 0; p < 2; p++) {
            __builtin_amdgcn_wave_barrier();   // order vs previous phase's P reads
            #pragma unroll
            for (int k2 = 0; k2 < 2; k2++) {
                int ib = p * 2 + k2;
                #pragma unroll
                for (int f = 0; f < 4; f++) {
                    float p0 = __expf(sc[ib][f][0] - mnew);
                    float p1 = __expf(sc[ib][f][1] - mnew);
                    float p2 = __expf(sc[ib][f][2] - mnew);
                    float p3 = __expf(sc[ib][f][3] - mnew);
                    rs += (p0 + p1) + (p2 + p3);
                    union { bf16 hh[4]; uint2 u; } pu;
                    pu.hh[0] = (bf16)p0; pu.hh[1] = (bf16)p1;
                    pu.hh[2] = (bf16)p2; pu.hh[3] = (bf16)p3;
                    *reinterpret_cast<uint2*>(pw + lm * 136 + k2 * 64 + f * 16 + quad * 4) = pu.u;
                }
            }
            __builtin_amdgcn_wave_barrier();   // writes before reads (cross-lane)
            #pragma unroll
            for (int k2 = 0; k2 < 2; k2++) {
                int ib = p * 2 + k2;
                int kb = fullmode ? (wave * 8 + ch * 4 + ib) : blist[half * 4 + ib];
                const bf16* vtb = vt + (size_t)bh * HD * SEQ + (size_t)kb * BLK;
                bf16x8 pb0 = *reinterpret_cast<const bf16x8*>(pw + lm * 136 + k2 * 64 + quad * 8);
                bf16x8 pb1 = *reinterpret_cast<const bf16x8*>(pw + lm * 136 + k2 * 64 + 32 + quad * 8);
                #pragma unroll
                for (int dj = 0; dj < 4; dj++) {
                    bf16x8 aV0 = *reinterpret_cast<const bf16x8*>(
                        vtb + (size_t)(dj * 16 + lm) * SEQ + quad * 8);
                    bf16x8 aV1 = *reinterpret_cast<const bf16x8*>(
                        vtb + (size_t)(dj * 16 + lm) * SEQ + 32 + quad * 8);
                    ctx[dj] = mfma16(aV0, pb0, ctx[dj]);
                    ctx[dj] = mfma16(aV1, pb1, ctx[dj]);
                }
            }
        }
        rs += __shfl_xor(rs, 16, 64);
        rs += __shfl_xor(rs, 32, 64);
        lrun += rs;
    }

    // ---- write partials, combine in LDS ----
    float* ctxL = (float*)smem;                    // [8][d=64][q=16] (overlays P)
    float* mL   = (float*)(smem + 32768);          // [8][16]
    float* lL   = (float*)(smem + 32768 + 512);    // [8][16]
    __syncthreads();   // all waves done with pw (region overlaps ctxL)
    #pragma unroll
    for (int dj = 0; dj < 4; dj++)
        #pragma unroll
        for (int r = 0; r < 4; r++)
            ctxL[wave * 1024 + (dj * 16 + quad * 4 + r) * 16 + lm] = ctx[dj][r];
    if (quad == 0) { mL[wave * 16 + lm] = mrun; lL[wave * 16 + lm] = lrun; }
    __syncthreads();

    if (fullmode) {
        // 8 partials over the same 16 queries; 512 threads -> 2 d's each
        int qq = tid & 15, dbase = (tid >> 4) * 2;
        float M = -1e30f;
        for (int w = 0; w < 8; w++) M = fmaxf(M, mL[w * 16 + qq]);
        float e[8], Lt = 0.f;
        for (int w = 0; w < 8; w++) { e[w] = __expf(mL[w * 16 + qq] - M); Lt += lL[w * 16 + qq] * e[w]; }
        int sq = l * BLK + sub * 16 + qq;
        float wgt = (1.f / Lt) * fromm[(size_t)b * SEQ + sq];
        union { bf16 hh[2]; unsigned int u; } o;
        #pragma unroll
        for (int dd = 0; dd < 2; dd++) {
            float acc = 0.f;
            for (int w = 0; w < 8; w++) acc += ctxL[w * 1024 + (dbase + dd) * 16 + qq] * e[w];
            o.hh[dd] = (bf16)(acc * wgt);
        }
        *reinterpret_cast<unsigned int*>(attn + ((size_t)(b * SEQ + sq)) * HID + h * HD + dbase) = o.u;
    } else {
        // pairwise combine: subtile s from waves s and s+4; 128 threads per subtile
        int s = tid >> 7, t = tid & 127;
        int qq = t & 15, dbase = (t >> 4) * 8;
        float m0 = mL[s * 16 + qq], m1 = mL[(s + 4) * 16 + qq];
        float M = fmaxf(m0, m1);
        float e0 = __expf(m0 - M), e1 = __expf(m1 - M);
        float Lt = lL[s * 16 + qq] * e0 + lL[(s + 4) * 16 + qq] * e1;
        int sq = l * BLK + s * 16 + qq;
        float wgt = (1.f / Lt) * fromm[(size_t)b * SEQ + sq];
        union { bf16 hh[8]; uint4 u; } o;
        #pragma unroll
        for (int dd = 0; dd < 8; dd++) {
            float acc = ctxL[s * 1024 + (dbase + dd) * 16 + qq] * e0
                      + ctxL[(s + 4) * 1024 + (dbase + dd) * 16 + qq] * e1;
            o.hh[dd] = (bf16)(acc * wgt);
        }
        *reinterpret_cast<uint4*>(attn + ((size_t)(b * SEQ + sq)) * HID + h * HD + dbase) = o.u;
    }
}

// ---------------- GEMM2: output projection ----------------
// 1-D grid, XCD-striped like gemm_qkv.
__global__ __launch_bounds__(256) void gemm_out(const bf16* __restrict__ A,
                                                const bf16* __restrict__ WoT,
                                                const float* __restrict__ bo,
                                                float* __restrict__ out) {
    __shared__ __align__(16) bf16 As[128 * 64];
    __shared__ __align__(16) bf16 Bs[128 * 64];
    int tid = threadIdx.x;
    int wave = tid >> 6, lane = tid & 63;
    int quad = lane >> 4, lm = lane & 15;
    int id = blockIdx.x;
    int xcd = id & 7, slot = id >> 3;
    int tile_m = (xcd * 8 + (slot & 7)) * 128;
    int tile_n = (slot >> 3) * 128;
    int wm = (wave & 1) * 64, wn = (wave >> 1) * 64;

    floatx4 acc[4][4] = {};

    for (int k0 = 0; k0 < HID; k0 += 64) {
        __syncthreads();
        for (int it = 0; it < 4; it++) {
            int c = it * 256 + tid;
            int row = c >> 3, col = (c & 7) * 8;
            async_ld16(A + (size_t)(tile_m + row) * HID + k0 + col, &As[c * 8]);
            async_ld16(WoT + (size_t)(tile_n + row) * HID + k0 + col, &Bs[c * 8]);
        }
        __syncthreads();
        for (int ks = 0; ks < 64; ks += 32) {
            bf16x8 a[4], b[4];
            for (int i = 0; i < 4; i++)
                a[i] = *reinterpret_cast<const bf16x8*>(&As[(wm + i * 16 + lm) * 64 + ks + quad * 8]);
            for (int j = 0; j < 4; j++)
                b[j] = *reinterpret_cast<const bf16x8*>(&Bs[(wn + j * 16 + lm) * 64 + ks + quad * 8]);
            for (int i = 0; i < 4; i++)
                for (int j = 0; j < 4; j++)
                    acc[i][j] = mfma16(a[i], b[j], acc[i][j]);
        }
    }

    for (int i = 0; i < 4; i++) {
        for (int j = 0; j < 4; j++) {
            int nn = tile_n + wn + j * 16 + lm;
            float bsv = bo[nn];
            for (int r = 0; r < 4; r++) {
                int mm = tile_m + wm + i * 16 + quad * 4 + r;
                int b_ = mm >> 12, s = mm & 4095;
                if (s < LQ)
                    out[((size_t)(b_ * LQ + s)) * HID + nn] = acc[i][j][r] + bsv;
            }
        }
    }
}

// ---------------- launcher ----------------
extern "C" void kernel_launch(void* const* d_in, const int* in_sizes, int n_in,
                              void* d_out, int out_size, void* d_ws, size_t ws_size,
                              hipStream_t stream) {
    const float* X       = (const float*)d_in[0];
    const float* Wq      = (const float*)d_in[1];
    const float* bq      = (const float*)d_in[2];
    const float* Wk      = (const float*)d_in[3];
    const float* bk      = (const float*)d_in[4];
    const float* Wv      = (const float*)d_in[5];
    const float* bv      = (const float*)d_in[6];
    const float* Wo      = (const float*)d_in[7];
    const float* bo      = (const float*)d_in[8];
    const float* band    = (const float*)d_in[9];
    const float* fromm   = (const float*)d_in[10];
    const float* tom     = (const float*)d_in[11];
    const float* blocked = (const float*)d_in[12];
    const int*   randa   = (const int*)d_in[13];
    float* out = (float*)d_out;

    char* ws = (char*)d_ws;
    bf16* Xp    = (bf16*)(ws + 0);              // 16,777,216 B (reused as attn)
    bf16* WqkvT = (bf16*)(ws + 16777216);       //  6,291,456 B (reused as bandT+flags after gemm_qkv)
    bf16* WoT   = (bf16*)(ws + 23068672);       //  2,097,152 B
    bf16* qb    = (bf16*)(ws + 25165824);       // 16,777,216 B
    bf16* kb    = (bf16*)(ws + 41943040);       // 16,777,216 B
    bf16* vtb   = (bf16*)(ws + 58720256);       // 16,777,216 B (d-major V)
    bf16* attnb = Xp;                           // Xp dead after gemm_qkv
    float* bandT = (float*)WqkvT;               // 5,898,240 B, alive only during attn
    int* flagsp = (int*)(ws + 16777216 + 5898240);  // 24 B, inside dead WqkvT tail

    cast_pad_x<<<dim3(8192), dim3(256), 0, stream>>>(X, Xp);
    transpose_w<<<dim3(16, 16, 4), dim3(64, 4), 0, stream>>>(Wq, Wk, Wv, Wo, WqkvT, WoT);
    gemm_qkv<<<dim3(1536), dim3(256), 0, stream>>>(Xp, WqkvT, bq, bk, bv, qb, kb, vtb);
    transpose_band<<<dim3(3, NB - 4, BB), dim3(64, 4), 0, stream>>>(band, bandT);
    mask_flags<<<dim3(3, BB), dim3(256), 0, stream>>>(tom, blocked, band, flagsp);
    attn_kernel<<<dim3(BB * NH, 70), dim3(512), 0, stream>>>(qb, kb, vtb, bandT, fromm, tom,
                                                             blocked, randa, flagsp, attnb);
    gemm_out<<<dim3(512), dim3(256), 0, stream>>>(attnb, WoT, bo, out);
}

// Round 9
// 387.994 us; speedup vs baseline: 1.6665x; 1.6665x over previous
//
#include <hip/hip_runtime.h>

// ---------------- constants ----------------
#define BB 2
#define SEQ 4096
#define LQ 4064
#define HID 1024
#define NH 16
#define HD 64
#define NB 64      // number of 64-wide blocks in sequence
#define BLK 64
#define NR 3
#define PENV -10000.0f

typedef __bf16 bf16;
typedef __bf16 bf16x8 __attribute__((ext_vector_type(8)));
typedef float floatx4 __attribute__((ext_vector_type(4)));

__device__ inline floatx4 mfma16(bf16x8 a, bf16x8 b, floatx4 c) {
    return __builtin_amdgcn_mfma_f32_16x16x32_bf16(a, b, c, 0, 0, 0);
}

// async global->LDS, 16B per lane (global_load_lds_dwordx4)
__device__ inline void async_ld16(const bf16* g, bf16* l) {
    __builtin_amdgcn_global_load_lds(
        (const __attribute__((address_space(1))) unsigned int*)g,
        (__attribute__((address_space(3))) unsigned int*)l, 16, 0, 0);
}

// ---------------- prep: pad + cast X to bf16 ----------------
__global__ __launch_bounds__(256) void cast_pad_x(const float* __restrict__ X,
                                                  bf16* __restrict__ Xp) {
    int t = blockIdx.x * 256 + threadIdx.x;
    int c4 = t & 255;
    int row = t >> 8;
    int b = row >> 12;
    int s = row & 4095;
    float4 v = make_float4(0.f, 0.f, 0.f, 0.f);
    if (s < LQ) {
        v = reinterpret_cast<const float4*>(X + ((size_t)(b * LQ + s)) * HID)[c4];
    }
    union { bf16 h[4]; uint2 u; } o;
    o.h[0] = (bf16)v.x; o.h[1] = (bf16)v.y; o.h[2] = (bf16)v.z; o.h[3] = (bf16)v.w;
    *reinterpret_cast<uint2*>(Xp + (size_t)row * HID + c4 * 4) = o.u;
}

// ---------------- prep: transpose + cast weights ----------------
__global__ __launch_bounds__(256) void transpose_w(const float* __restrict__ Wq,
                                                   const float* __restrict__ Wk,
                                                   const float* __restrict__ Wv,
                                                   const float* __restrict__ Wo,
                                                   bf16* __restrict__ WqkvT,
                                                   bf16* __restrict__ WoT) {
    __shared__ float tile[64][65];
    int sel = blockIdx.z;
    const float* src = (sel == 0) ? Wq : (sel == 1) ? Wk : (sel == 2) ? Wv : Wo;
    bf16* dst = (sel < 3) ? (WqkvT + (size_t)sel * HID * HID) : WoT;
    int j0 = blockIdx.x * 64, k0 = blockIdx.y * 64;
    int tx = threadIdx.x, ty = threadIdx.y;   // (64,4)
    for (int i = 0; i < 16; i++) {
        int k = ty + i * 4;
        tile[k][tx] = src[(size_t)(k0 + k) * HID + j0 + tx];
    }
    __syncthreads();
    for (int i = 0; i < 16; i++) {
        int j = ty + i * 4;
        dst[(size_t)(j0 + j) * HID + k0 + tx] = (bf16)tile[tx][j];
    }
}

// ---------------- prep: transpose band mask ----------------
// band[b][l][q=64][k=192] -> bandT[b][l][k=192][q=64]
__global__ __launch_bounds__(256) void transpose_band(const float* __restrict__ band,
                                                      float* __restrict__ bandT) {
    __shared__ float tile[64][65];
    int kt = blockIdx.x;           // 0..2
    int lrow = blockIdx.y;         // 0..59
    int b = blockIdx.z;
    const float* src = band + ((size_t)(b * (NB - 4) + lrow) * BLK) * 192;
    float* dst = bandT + ((size_t)(b * (NB - 4) + lrow) * 192) * BLK;
    int tx = threadIdx.x, ty = threadIdx.y;   // (64,4)
    for (int i = 0; i < 16; i++) {
        int qq = i * 4 + ty;
        tile[qq][tx] = src[(size_t)qq * 192 + kt * 64 + tx];
    }
    __syncthreads();
    for (int i = 0; i < 16; i++) {
        int k = i * 4 + ty;
        dst[(size_t)(kt * 64 + k) * BLK + tx] = tile[tx][k];
    }
}

// ---------------- prep: mask violation flags (parallel) ----------------
// flags[which*BB+b] = 1 if ANY element != 1.0f (flags pre-zeroed via memset).
// which: 0=to_mask, 1=blocked, 2=band. grid (240, 3, BB), grid-stride.
__global__ __launch_bounds__(256) void mask_viol(const float* __restrict__ tom,
                                                 const float* __restrict__ blocked,
                                                 const float* __restrict__ band,
                                                 int* __restrict__ flags) {
    int which = blockIdx.y, b = blockIdx.z;
    const float* src;
    size_t n;
    if (which == 0)      { src = tom     + (size_t)b * SEQ;                  n = SEQ; }
    else if (which == 1) { src = blocked + (size_t)b * NB * BLK;             n = NB * BLK; }
    else                 { src = band    + (size_t)b * (NB - 4) * BLK * 192; n = (size_t)(NB - 4) * BLK * 192; }
    const float4* s4 = (const float4*)src;
    size_t n4 = n >> 2;
    int bad = 0;
    for (size_t i = blockIdx.x * 256 + threadIdx.x; i < n4; i += 240 * 256) {
        float4 v = s4[i];
        bad |= (v.x != 1.0f) | (v.y != 1.0f) | (v.z != 1.0f) | (v.w != 1.0f);
    }
    if (__any(bad) && (threadIdx.x & 63) == 0)
        atomicOr(&flags[which * BB + b], 1);
}

// ---------------- GEMM1: QKV projection ----------------
// 1-D grid, XCD-striped; LDS-transposed coalesced epilogue ([s][d] q/k, [d][s] v).
__global__ __launch_bounds__(256) void gemm_qkv(const bf16* __restrict__ Xp,
                                                const bf16* __restrict__ WT,
                                                const float* __restrict__ bq,
                                                const float* __restrict__ bk,
                                                const float* __restrict__ bv,
                                                bf16* __restrict__ qo,
                                                bf16* __restrict__ ko,
                                                bf16* __restrict__ vt) {
    __shared__ __align__(16) char smem[36864];   // staging 32KB; epi 4x9216B overlays
    bf16* As = (bf16*)smem;            // [128][64]
    bf16* Bs = As + 128 * 64;          // [128][64]
    int tid = threadIdx.x;
    int wave = tid >> 6, lane = tid & 63;
    int quad = lane >> 4, lm = lane & 15;
    int id = blockIdx.x;
    int xcd = id & 7, slot = id >> 3;
    int tile_m = (xcd * 8 + (slot & 7)) * 128;   // 64 tile_m rows across 8 XCDs
    int tile_n = (slot >> 3) * 128;              // 24 tile_n cols
    int wm = (wave & 1) * 64, wn = (wave >> 1) * 64;

    floatx4 acc[4][4] = {};

    for (int k0 = 0; k0 < HID; k0 += 64) {
        __syncthreads();
        for (int it = 0; it < 4; it++) {
            int c = it * 256 + tid;           // LDS offset = c*16B (lane-contig)
            int row = c >> 3, col = (c & 7) * 8;
            async_ld16(Xp + (size_t)(tile_m + row) * HID + k0 + col, &As[c * 8]);
            async_ld16(WT + (size_t)(tile_n + row) * HID + k0 + col, &Bs[c * 8]);
        }
        __syncthreads();
        for (int ks = 0; ks < 64; ks += 32) {
            bf16x8 a[4], b[4];
            for (int i = 0; i < 4; i++)
                a[i] = *reinterpret_cast<const bf16x8*>(&As[(wm + i * 16 + lm) * 64 + ks + quad * 8]);
            for (int j = 0; j < 4; j++)
                b[j] = *reinterpret_cast<const bf16x8*>(&Bs[(wn + j * 16 + lm) * 64 + ks + quad * 8]);
            for (int i = 0; i < 4; i++)
                for (int j = 0; j < 4; j++)
                    acc[i][j] = mfma16(a[i], b[j], acc[i][j]);
        }
    }

    int which = tile_n >> 10;                 // 0=q,1=k,2=v (wave-uniform)
    int hc_base = (tile_n + wn) & 1023;       // multiple of 64
    int h = hc_base >> 6;
    const float* bias = (which == 0) ? bq : (which == 1) ? bk : bv;
    __syncthreads();                          // retire all staging reads before overlay
    bf16* ep = (bf16*)smem + wave * (64 * 72);

    if (which < 2) {
        #pragma unroll
        for (int i = 0; i < 4; i++)
            #pragma unroll
            for (int j = 0; j < 4; j++) {
                float bsv = bias[hc_base + j * 16 + lm];
                #pragma unroll
                for (int r = 0; r < 4; r++) {
                    float val = acc[i][j][r] + bsv;
                    if (which == 0) val *= 0.125f;
                    ep[(i * 16 + quad * 4 + r) * 72 + j * 16 + lm] = (bf16)val;
                }
            }
        __builtin_amdgcn_wave_barrier();
        int s_glob = tile_m + wm + lane;
        int b_ = s_glob >> 12, s = s_glob & 4095;
        bf16* dstb = ((which == 0) ? qo : ko) + ((size_t)((b_ * NH + h) * SEQ + s)) * HD;
        #pragma unroll
        for (int c = 0; c < 8; c++)
            *reinterpret_cast<uint4*>(dstb + c * 8) =
                *reinterpret_cast<const uint4*>(ep + lane * 72 + c * 8);
    } else {
        #pragma unroll
        for (int i = 0; i < 4; i++)
            #pragma unroll
            for (int j = 0; j < 4; j++) {
                float bsv = bias[hc_base + j * 16 + lm];
                #pragma unroll
                for (int r = 0; r < 4; r++) {
                    float val = acc[i][j][r] + bsv;
                    ep[(j * 16 + lm) * 72 + i * 16 + quad * 4 + r] = (bf16)val;
                }
            }
        __builtin_amdgcn_wave_barrier();
        int s_base = tile_m + wm;
        int b_ = s_base >> 12, s0 = s_base & 4095;
        bf16* dstb = vt + ((size_t)((b_ * NH + h) * HD + lane)) * SEQ + s0;
        #pragma unroll
        for (int c = 0; c < 8; c++)
            *reinterpret_cast<uint4*>(dstb + c * 8) =
                *reinterpret_cast<const uint4*>(ep + lane * 72 + c * 8);
    }
}

// ---------------- attention (round-7 structure + wave-uniform mask skip) ----------------
// grid: (B*NH, 70). blockIdx.x = bh -> XCD-resident K/V per (b,h).
// y<8: full rows (l=0/63), sub=y&3, 4 waves x 16 blocks (4 chunks), LDS combine.
// y>=8: middle row l=y-7, sub=wave, 2 chunks of 4 (8 padded slots), wave-independent.
// Mask penalties skipped wave-uniformly when flag==0 (mask all-ones; exact: (1-1)*PEN=0).
__global__ __launch_bounds__(256, 2) void attn_kernel(const bf16* __restrict__ q,
                                                      const bf16* __restrict__ kk,
                                                      const bf16* __restrict__ vt,
                                                      const float* __restrict__ bandT,
                                                      const float* __restrict__ fromm,
                                                      const float* __restrict__ tom,
                                                      const float* __restrict__ blocked,
                                                      const int* __restrict__ rand_attn,
                                                      const int* __restrict__ flags,
                                                      bf16* __restrict__ attn) {
    __shared__ __align__(16) char smem[33792 + 512];

    int tid = threadIdx.x, wave = tid >> 6, lane = tid & 63;
    int quad = lane >> 4, lm = lane & 15;
    int bh = blockIdx.x;
    int b = bh >> 4, h = bh & 15;
    size_t bh_base = (size_t)bh * SEQ * HD;
    int x = blockIdx.y;
    bool fullmode = (x < 8);
    int l, sub;
    if (fullmode) { l = (x >> 2) ? (NB - 1) : 0; sub = x & 3; }
    else          { l = x - 7;                   sub = wave;  }

    bool do_to = flags[b] != 0;          // to_mask has non-ones
    bool do_bl = flags[BB + b] != 0;     // blocked has non-ones
    bool do_bd = flags[2 * BB + b] != 0; // band has non-ones

    // Q fragments (B-operand: n=query=lm, k=d=quad*8+j); q pre-scaled by 1/sqrt(D)
    bf16x8 aq0 = *reinterpret_cast<const bf16x8*>(
        q + bh_base + (size_t)(l * BLK + sub * 16 + lm) * HD + quad * 8);
    bf16x8 aq1 = *reinterpret_cast<const bf16x8*>(
        q + bh_base + (size_t)(l * BLK + sub * 16 + lm) * HD + 32 + quad * 8);

    floatx4 ctx[4] = {};        // O^T: d=dj*16+quad*4+r, query=lm
    float mrun = -1e30f, lrun = 0.f;
    float mq = blocked[((size_t)b * NB + l) * BLK + sub * 16 + lm];  // per-lane query mask

    // key-block list (middle mode), padded to 8. type: 0=to_mask, 1..3=band(t), 4=rand, 5=pad
    int blist[8], btype[8];
    if (!fullmode) {
        int base;
        if (l == 1) {
            blist[0] = 0; blist[1] = 1; blist[2] = 2; blist[3] = NB - 1;
            btype[0] = btype[1] = btype[2] = btype[3] = 0;
            base = 4;
        } else if (l == NB - 2) {
            blist[0] = 0; blist[1] = NB - 3; blist[2] = NB - 2; blist[3] = NB - 1;
            btype[0] = btype[1] = btype[2] = btype[3] = 0;
            base = 4;
        } else {
            blist[0] = 0;      btype[0] = 0;
            blist[1] = l - 1;  btype[1] = 1;
            blist[2] = l;      btype[2] = 2;
            blist[3] = l + 1;  btype[3] = 3;
            blist[4] = NB - 1; btype[4] = 0;
            base = 5;
        }
        const int* ra = rand_attn + ((size_t)(b * NH + h) * (NB - 2) + (l - 1)) * NR;
        for (int r = 0; r < NR; r++) { blist[base + r] = ra[r]; btype[base + r] = 4; }
        for (int i = base + NR; i < 8; i++) { blist[i] = 0; btype[i] = 5; }
    }

    bf16* pw = (bf16*)smem + wave * 16 * 264;  // [q=16][key stride 264] (holds 4 blocks)

    int nch = fullmode ? 4 : 2;
    for (int ch = 0; ch < nch; ch++) {
        // ---- scores: S^T = K * Q^T; sc[ib][f][r] = S^T[key=f*16+quad*4+r][q=lm] ----
        floatx4 sc[4][4];
        #pragma unroll
        for (int ib = 0; ib < 4; ib++) {
            int kb  = fullmode ? (wave * 16 + ch * 4 + ib) : blist[ch * 4 + ib];
            int typ = fullmode ? 0 : btype[ch * 4 + ib];
            const bf16* kbase = kk + bh_base + (size_t)kb * BLK * HD;
            #pragma unroll
            for (int f = 0; f < 4; f++) {
                bf16x8 a0 = *reinterpret_cast<const bf16x8*>(kbase + (f * 16 + lm) * HD + quad * 8);
                bf16x8 a1 = *reinterpret_cast<const bf16x8*>(kbase + (f * 16 + lm) * HD + 32 + quad * 8);
                floatx4 z = {0.f, 0.f, 0.f, 0.f};
                z = mfma16(a0, aq0, z);
                z = mfma16(a1, aq1, z);
                sc[ib][f] = z;
            }
            // masks (key = f*16+quad*4+r, query = lm); skipped when mask all-ones
            if (typ == 0) {
                if (do_to) {
                    #pragma unroll
                    for (int f = 0; f < 4; f++) {
                        float4 t4 = *reinterpret_cast<const float4*>(
                            tom + (size_t)b * SEQ + kb * BLK + f * 16 + quad * 4);
                        sc[ib][f][0] += (1.f - t4.x) * PENV;
                        sc[ib][f][1] += (1.f - t4.y) * PENV;
                        sc[ib][f][2] += (1.f - t4.z) * PENV;
                        sc[ib][f][3] += (1.f - t4.w) * PENV;
                    }
                }
            } else if (typ == 4) {
                if (do_bl) {
                    #pragma unroll
                    for (int f = 0; f < 4; f++) {
                        float4 t4 = *reinterpret_cast<const float4*>(
                            blocked + ((size_t)b * NB + kb) * BLK + f * 16 + quad * 4);
                        sc[ib][f][0] += (1.f - mq * t4.x) * PENV;
                        sc[ib][f][1] += (1.f - mq * t4.y) * PENV;
                        sc[ib][f][2] += (1.f - mq * t4.z) * PENV;
                        sc[ib][f][3] += (1.f - mq * t4.w) * PENV;
                    }
                }
            } else if (typ != 5) {
                if (do_bd) {
                    int t = typ - 1;
                    const float* bp = bandT + ((size_t)(b * (NB - 4) + (l - 2)) * 192 + t * 64) * BLK;
                    #pragma unroll
                    for (int f = 0; f < 4; f++)
                        #pragma unroll
                        for (int r = 0; r < 4; r++) {
                            float bm = bp[(size_t)(f * 16 + quad * 4 + r) * BLK + sub * 16 + lm];
                            sc[ib][f][r] += (1.f - bm) * PENV;
                        }
                }
            } else {
                #pragma unroll
                for (int f = 0; f < 4; f++)
                    #pragma unroll
                    for (int r = 0; r < 4; r++) sc[ib][f][r] += PENV;
            }
        }

        // ---- softmax over the chunk (per-lane m; 2 shuffles) ----
        float mx = -1e30f;
        #pragma unroll
        for (int ib = 0; ib < 4; ib++)
            #pragma unroll
            for (int f = 0; f < 4; f++)
                #pragma unroll
                for (int r = 0; r < 4; r++) mx = fmaxf(mx, sc[ib][f][r]);
        mx = fmaxf(mx, __shfl_xor(mx, 16, 64));
        mx = fmaxf(mx, __shfl_xor(mx, 32, 64));
        float mnew = fmaxf(mrun, mx);
        float scale = __expf(mrun - mnew);
        lrun *= scale;
        #pragma unroll
        for (int dj = 0; dj < 4; dj++) ctx[dj] *= scale;
        mrun = mnew;

        // ---- exp -> P^T for ALL 4 blocks into per-wave LDS (one write phase) ----
        __builtin_amdgcn_wave_barrier();   // order vs previous chunk's P reads
        float rs = 0.f;
        #pragma unroll
        for (int ib = 0; ib < 4; ib++)
            #pragma unroll
            for (int f = 0; f < 4; f++) {
                float p0 = __expf(sc[ib][f][0] - mnew);
                float p1 = __expf(sc[ib][f][1] - mnew);
                float p2 = __expf(sc[ib][f][2] - mnew);
                float p3 = __expf(sc[ib][f][3] - mnew);
                rs += (p0 + p1) + (p2 + p3);
                union { bf16 hh[4]; uint2 u; } pu;
                pu.hh[0] = (bf16)p0; pu.hh[1] = (bf16)p1;
                pu.hh[2] = (bf16)p2; pu.hh[3] = (bf16)p3;
                *reinterpret_cast<uint2*>(pw + lm * 264 + ib * 64 + f * 16 + quad * 4) = pu.u;
            }
        __builtin_amdgcn_wave_barrier();   // writes before reads (cross-lane)
        rs += __shfl_xor(rs, 16, 64);
        rs += __shfl_xor(rs, 32, 64);
        lrun += rs;

        // ---- PV^T: all 4 blocks, no barriers between (loads pipeline freely) ----
        #pragma unroll
        for (int ib = 0; ib < 4; ib++) {
            int kb = fullmode ? (wave * 16 + ch * 4 + ib) : blist[ch * 4 + ib];
            const bf16* vtb = vt + (size_t)bh * HD * SEQ + (size_t)kb * BLK;
            bf16x8 pb0 = *reinterpret_cast<const bf16x8*>(pw + lm * 264 + ib * 64 + quad * 8);
            bf16x8 pb1 = *reinterpret_cast<const bf16x8*>(pw + lm * 264 + ib * 64 + 32 + quad * 8);
            #pragma unroll
            for (int dj = 0; dj < 4; dj++) {
                bf16x8 aV0 = *reinterpret_cast<const bf16x8*>(
                    vtb + (size_t)(dj * 16 + lm) * SEQ + quad * 8);
                bf16x8 aV1 = *reinterpret_cast<const bf16x8*>(
                    vtb + (size_t)(dj * 16 + lm) * SEQ + 32 + quad * 8);
                ctx[dj] = mfma16(aV0, pb0, ctx[dj]);
                ctx[dj] = mfma16(aV1, pb1, ctx[dj]);
            }
        }
    }

    if (!fullmode) {
        // per-lane finalize: query = lm
        int sq = l * BLK + sub * 16 + lm;
        float w = (1.f / lrun) * fromm[(size_t)b * SEQ + sq];
        bf16* dst = attn + ((size_t)(b * SEQ + sq)) * HID + h * HD;
        #pragma unroll
        for (int dj = 0; dj < 4; dj++) {
            union { bf16 hh[4]; uint2 u; } o;
            #pragma unroll
            for (int r = 0; r < 4; r++) o.hh[r] = (bf16)(ctx[dj][r] * w);
            *reinterpret_cast<uint2*>(dst + dj * 16 + quad * 4) = o.u;
        }
    } else {
        // cross-wave combine (4 partials over the same 16 queries)
        float* ctxL = (float*)smem;                    // [wave][d=64][q=16] (overlays P)
        float* mL   = (float*)(smem + 33792);          // [wave][16]
        float* lL   = (float*)(smem + 33792 + 256);    // [wave][16]
        __syncthreads();   // all waves done with pw (region overlaps ctxL)
        #pragma unroll
        for (int dj = 0; dj < 4; dj++)
            #pragma unroll
            for (int r = 0; r < 4; r++)
                ctxL[wave * 1024 + (dj * 16 + quad * 4 + r) * 16 + lm] = ctx[dj][r];
        if (quad == 0) { mL[wave * 16 + lm] = mrun; lL[wave * 16 + lm] = lrun; }
        __syncthreads();
        int qq = tid & 15, dbase = (tid >> 4) * 4;
        float M = -1e30f;
        for (int w = 0; w < 4; w++) M = fmaxf(M, mL[w * 16 + qq]);
        float e[4], Lt = 0.f;
        for (int w = 0; w < 4; w++) { e[w] = __expf(mL[w * 16 + qq] - M); Lt += lL[w * 16 + qq] * e[w]; }
        int sq = l * BLK + sub * 16 + qq;
        float wgt = (1.f / Lt) * fromm[(size_t)b * SEQ + sq];
        union { bf16 hh[4]; uint2 u; } o;
        #pragma unroll
        for (int dd = 0; dd < 4; dd++) {
            float acc = 0.f;
            for (int w = 0; w < 4; w++) acc += ctxL[w * 1024 + (dbase + dd) * 16 + qq] * e[w];
            o.hh[dd] = (bf16)(acc * wgt);
        }
        *reinterpret_cast<uint2*>(attn + ((size_t)(b * SEQ + sq)) * HID + h * HD + dbase) = o.u;
    }
}

// ---------------- GEMM2: output projection ----------------
// 1-D grid, XCD-striped like gemm_qkv.
__global__ __launch_bounds__(256) void gemm_out(const bf16* __restrict__ A,
                                                const bf16* __restrict__ WoT,
                                                const float* __restrict__ bo,
                                                float* __restrict__ out) {
    __shared__ __align__(16) bf16 As[128 * 64];
    __shared__ __align__(16) bf16 Bs[128 * 64];
    int tid = threadIdx.x;
    int wave = tid >> 6, lane = tid & 63;
    int quad = lane >> 4, lm = lane & 15;
    int id = blockIdx.x;
    int xcd = id & 7, slot = id >> 3;
    int tile_m = (xcd * 8 + (slot & 7)) * 128;
    int tile_n = (slot >> 3) * 128;
    int wm = (wave & 1) * 64, wn = (wave >> 1) * 64;

    floatx4 acc[4][4] = {};

    for (int k0 = 0; k0 < HID; k0 += 64) {
        __syncthreads();
        for (int it = 0; it < 4; it++) {
            int c = it * 256 + tid;
            int row = c >> 3, col = (c & 7) * 8;
            async_ld16(A + (size_t)(tile_m + row) * HID + k0 + col, &As[c * 8]);
            async_ld16(WoT + (size_t)(tile_n + row) * HID + k0 + col, &Bs[c * 8]);
        }
        __syncthreads();
        for (int ks = 0; ks < 64; ks += 32) {
            bf16x8 a[4], b[4];
            for (int i = 0; i < 4; i++)
                a[i] = *reinterpret_cast<const bf16x8*>(&As[(wm + i * 16 + lm) * 64 + ks + quad * 8]);
            for (int j = 0; j < 4; j++)
                b[j] = *reinterpret_cast<const bf16x8*>(&Bs[(wn + j * 16 + lm) * 64 + ks + quad * 8]);
            for (int i = 0; i < 4; i++)
                for (int j = 0; j < 4; j++)
                    acc[i][j] = mfma16(a[i], b[j], acc[i][j]);
        }
    }

    for (int i = 0; i < 4; i++) {
        for (int j = 0; j < 4; j++) {
            int nn = tile_n + wn + j * 16 + lm;
            float bsv = bo[nn];
            for (int r = 0; r < 4; r++) {
                int mm = tile_m + wm + i * 16 + quad * 4 + r;
                int b_ = mm >> 12, s = mm & 4095;
                if (s < LQ)
                    out[((size_t)(b_ * LQ + s)) * HID + nn] = acc[i][j][r] + bsv;
            }
        }
    }
}

// ---------------- launcher ----------------
extern "C" void kernel_launch(void* const* d_in, const int* in_sizes, int n_in,
                              void* d_out, int out_size, void* d_ws, size_t ws_size,
                              hipStream_t stream) {
    const float* X       = (const float*)d_in[0];
    const float* Wq      = (const float*)d_in[1];
    const float* bq      = (const float*)d_in[2];
    const float* Wk      = (const float*)d_in[3];
    const float* bk      = (const float*)d_in[4];
    const float* Wv      = (const float*)d_in[5];
    const float* bv      = (const float*)d_in[6];
    const float* Wo      = (const float*)d_in[7];
    const float* bo      = (const float*)d_in[8];
    const float* band    = (const float*)d_in[9];
    const float* fromm   = (const float*)d_in[10];
    const float* tom     = (const float*)d_in[11];
    const float* blocked = (const float*)d_in[12];
    const int*   randa   = (const int*)d_in[13];
    float* out = (float*)d_out;

    char* ws = (char*)d_ws;
    bf16* Xp    = (bf16*)(ws + 0);              // 16,777,216 B (reused as attn)
    bf16* WqkvT = (bf16*)(ws + 16777216);       //  6,291,456 B (reused as bandT+flags after gemm_qkv)
    bf16* WoT   = (bf16*)(ws + 23068672);       //  2,097,152 B
    bf16* qb    = (bf16*)(ws + 25165824);       // 16,777,216 B
    bf16* kb    = (bf16*)(ws + 41943040);       // 16,777,216 B
    bf16* vtb   = (bf16*)(ws + 58720256);       // 16,777,216 B (d-major V)
    bf16* attnb = Xp;                           // Xp dead after gemm_qkv
    float* bandT = (float*)WqkvT;               // 5,898,240 B, alive only during attn
    int* flagsp = (int*)(ws + 16777216 + 5898240);  // 24 B, inside dead WqkvT tail

    cast_pad_x<<<dim3(8192), dim3(256), 0, stream>>>(X, Xp);
    transpose_w<<<dim3(16, 16, 4), dim3(64, 4), 0, stream>>>(Wq, Wk, Wv, Wo, WqkvT, WoT);
    gemm_qkv<<<dim3(1536), dim3(256), 0, stream>>>(Xp, WqkvT, bq, bk, bv, qb, kb, vtb);
    transpose_band<<<dim3(3, NB - 4, BB), dim3(64, 4), 0, stream>>>(band, bandT);
    hipMemsetAsync(flagsp, 0, 3 * BB * sizeof(int), stream);
    mask_viol<<<dim3(240, 3, BB), dim3(256), 0, stream>>>(tom, blocked, band, flagsp);
    attn_kernel<<<dim3(BB * NH, 70), dim3(256), 0, stream>>>(qb, kb, vtb, bandT, fromm, tom,
                                                             blocked, randa, flagsp, attnb);
    gemm_out<<<dim3(512), dim3(256), 0, stream>>>(attnb, WoT, bo, out);
}